// Round 1
// baseline (298.082 us; speedup 1.0000x reference)
//
#include <hip/hip_runtime.h>

typedef unsigned short u16;
typedef unsigned int   u32;
typedef float  f32x4  __attribute__((ext_vector_type(4)));
typedef __bf16 bf16x8 __attribute__((ext_vector_type(8)));
typedef unsigned short u16x8 __attribute__((ext_vector_type(8)));

// fp32 -> bf16 round-to-nearest-even
__device__ __forceinline__ u16 f2bf(float f) {
  u32 u = __builtin_bit_cast(u32, f);
  u = (u + 0x7fffu + ((u >> 16) & 1u)) >> 16;
  return (u16)u;
}

// async global->LDS, 16B per lane; LDS dest must be wave-uniform base (HW adds lane*16)
__device__ __forceinline__ void gload_lds16(const void* g, void* l) {
  __builtin_amdgcn_global_load_lds(
      (const __attribute__((address_space(1))) void*)g,
      (__attribute__((address_space(3))) void*)l, 16, 0, 0);
}

// ---------------------------------------------------------------------------
// fp32 -> bf16 elementwise (8 elems/thread)
__global__ __launch_bounds__(256) void conv_f32_bf16(
    const float* __restrict__ in, u16* __restrict__ out, int n8) {
  int i = blockIdx.x * 256 + threadIdx.x;
  if (i >= n8) return;
  const float4* p = (const float4*)in;
  float4 a = p[2 * i], b = p[2 * i + 1];
  u16x8 r;
  r[0] = f2bf(a.x); r[1] = f2bf(a.y); r[2] = f2bf(a.z); r[3] = f2bf(a.w);
  r[4] = f2bf(b.x); r[5] = f2bf(b.y); r[6] = f2bf(b.z); r[7] = f2bf(b.w);
  ((u16x8*)out)[i] = r;
}

// fp32 [K][N] -> bf16 [N][K] transpose (64x64 tiles via LDS)
__global__ __launch_bounds__(256) void conv_transpose(
    const float* __restrict__ in, u16* __restrict__ out, int K, int N) {
  __shared__ float tile[64][65];
  int nb = N >> 6;
  int tk = blockIdx.x / nb, tn = blockIdx.x % nb;
  int t = threadIdx.x;
  int kl = t >> 4, n4 = (t & 15) * 4;
#pragma unroll
  for (int i = 0; i < 4; ++i) {
    int k = kl + 16 * i;
    float4 v = *(const float4*)(in + (size_t)(tk * 64 + k) * N + tn * 64 + n4);
    tile[k][n4] = v.x; tile[k][n4 + 1] = v.y; tile[k][n4 + 2] = v.z; tile[k][n4 + 3] = v.w;
  }
  __syncthreads();
  int nl = t >> 4, k4 = (t & 15) * 4;
#pragma unroll
  for (int i = 0; i < 4; ++i) {
    int n = nl + 16 * i;
    ushort4 o;
    o.x = f2bf(tile[k4 + 0][n]); o.y = f2bf(tile[k4 + 1][n]);
    o.z = f2bf(tile[k4 + 2][n]); o.w = f2bf(tile[k4 + 3][n]);
    *(ushort4*)(out + (size_t)(tn * 64 + n) * K + tk * 64 + k4) = o;
  }
}

// ---------------------------------------------------------------------------
// bf16 GEMM: C[M][N] = A[M][K] * Bt[N][K]^T + bias ; 128x128 tile, BK=64,
// 4 waves (2x2), each wave 64x64 via 4x4 x mfma_f32_16x16x32_bf16.
// LDS tiles XOR-(row&7)-swizzled; staged by global_load_lds with pre-swizzled src.
template <int OUT_BF16>
__global__ __launch_bounds__(256, 2) void gemm_kernel(
    const u16* __restrict__ A, const u16* __restrict__ Bt,
    const float* __restrict__ bias, void* __restrict__ C,
    int M, int N, int K) {
  __shared__ __align__(16) char smem[32768];
  char* As = smem;
  char* Bs = smem + 16384;
  int tid = threadIdx.x, w = tid >> 6, lane = tid & 63;
  int g = lane >> 4, l15 = lane & 15, l7 = lane & 7;
  int nblk = N >> 7;
  int bm = blockIdx.x / nblk, bn = blockIdx.x % nblk;
  int m0 = bm << 7, n0 = bn << 7;
  int wm = w >> 1, wn = w & 1;

  f32x4 acc[4][4];
#pragma unroll
  for (int i = 0; i < 4; ++i)
#pragma unroll
    for (int j = 0; j < 4; ++j) acc[i][j] = f32x4{0.f, 0.f, 0.f, 0.f};

  int kiter = K >> 6;
  for (int kt = 0; kt < kiter; ++kt) {
    __syncthreads();
#pragma unroll
    for (int i = 0; i < 4; ++i) {
      int rbase = 32 * w + 8 * i;
      int row = rbase + (lane >> 3);
      int koff = kt * 64 + 8 * (l7 ^ (row & 7));
      gload_lds16(A + (size_t)(m0 + row) * K + koff, As + rbase * 128);
      gload_lds16(Bt + (size_t)(n0 + row) * K + koff, Bs + rbase * 128);
    }
    __syncthreads();
#pragma unroll
    for (int ks = 0; ks < 2; ++ks) {
      bf16x8 af[4], bf[4];
#pragma unroll
      for (int mi = 0; mi < 4; ++mi) {
        int ml = wm * 64 + mi * 16 + l15;
        af[mi] = *(const bf16x8*)(As + ml * 128 + ((ks * 64 + g * 16) ^ ((ml & 7) << 4)));
      }
#pragma unroll
      for (int ni = 0; ni < 4; ++ni) {
        int nl = wn * 64 + ni * 16 + l15;
        bf[ni] = *(const bf16x8*)(Bs + nl * 128 + ((ks * 64 + g * 16) ^ ((nl & 7) << 4)));
      }
#pragma unroll
      for (int mi = 0; mi < 4; ++mi)
#pragma unroll
        for (int ni = 0; ni < 4; ++ni)
          acc[mi][ni] = __builtin_amdgcn_mfma_f32_16x16x32_bf16(af[mi], bf[ni], acc[mi][ni], 0, 0, 0);
    }
  }

  // epilogue: D layout col=lane&15, row=(lane>>4)*4+r
#pragma unroll
  for (int ni = 0; ni < 4; ++ni) {
    int col = n0 + wn * 64 + ni * 16 + l15;
    float bv = bias[col];
#pragma unroll
    for (int mi = 0; mi < 4; ++mi) {
      int rowb = m0 + wm * 64 + mi * 16 + g * 4;
#pragma unroll
      for (int r = 0; r < 4; ++r) {
        float v = acc[mi][ni][r] + bv;
        if (OUT_BF16)
          ((u16*)C)[(size_t)(rowb + r) * N + col] = f2bf(v);
        else
          ((float*)C)[(size_t)(rowb + r) * N + col] = v;
      }
    }
  }
}

// ---------------------------------------------------------------------------
// Causal flash attention. qkv: bf16 [B*S][3072] rows = b*2048+s,
// q cols [0,1024), k cols [1024,2048), v cols [2048,3072), head h owns 64 cols.
// Block: one (b,h), 64 q-rows (qt tile); 4 waves x 16 q-rows. KVBLK=64.
__global__ __launch_bounds__(256, 2) void attn_fwd(
    const u16* __restrict__ qkv, u16* __restrict__ aout) {
  const int S = 2048, D3 = 3072;
  int bh = blockIdx.x & 63;
  int qt = 31 - (blockIdx.x >> 6);  // heavy tiles first
  int b = bh >> 4, h = bh & 15;
  const u16* qb = qkv + (size_t)b * S * D3;

  int tid = threadIdx.x;
  int w = tid >> 6, lane = tid & 63;
  int g = lane >> 4, l15 = lane & 15, l7 = lane & 7;

  __shared__ __align__(16) char Kb[8192];  // K tile [64 kv][64 d], (kv&7) swizzle
  __shared__ __align__(16) char Vb[8192];  // V^T tile [64 d][64 kv], ((d&7)^(d>>3)) swizzle
  __shared__ __align__(16) char Pb[8192];  // per-wave P [16 q][64 kv], (q&7) swizzle

  // Q fragments (A operand): rows qt*64 + w*16 + l15, k = ks*32 + 8g + j
  int qrow = qt * 64 + w * 16 + l15;
  const u16* qp = qb + (size_t)qrow * D3 + h * 64 + g * 8;
  bf16x8 qf0 = *(const bf16x8*)qp;
  bf16x8 qf1 = *(const bf16x8*)(qp + 32);

  f32x4 o_acc[4];
#pragma unroll
  for (int i = 0; i < 4; ++i) o_acc[i] = f32x4{0.f, 0.f, 0.f, 0.f};
  float m_r[4] = {-3e38f, -3e38f, -3e38f, -3e38f};
  float l_r[4] = {0.f, 0.f, 0.f, 0.f};

  char* pw = Pb + w * 2048;

  for (int kvt = 0; kvt <= qt; ++kvt) {
    __syncthreads();
    // stage K rows [16w, 16w+16) via global_load_lds, source pre-swizzled
#pragma unroll
    for (int i = 0; i < 2; ++i) {
      int rbase = w * 16 + i * 8;
      int row = rbase + (lane >> 3);
      const u16* src = qb + (size_t)(kvt * 64 + row) * D3 + 1024 + h * 64 + 8 * (l7 ^ (row & 7));
      gload_lds16(src, Kb + rbase * 128);
    }
    // reg-stage V transposed: thread owns kv pair (kv0,kv0+1) x 8 d
    {
      int kv0 = w * 16 + ((lane >> 3) << 1);
      int d0 = l7 * 8;
      const u16* vs = qb + (size_t)(kvt * 64 + kv0) * D3 + 2048 + h * 64 + d0;
      u16x8 v0 = *(const u16x8*)vs;
      u16x8 v1 = *(const u16x8*)(vs + D3);
#pragma unroll
      for (int j = 0; j < 8; ++j) {
        int d = d0 + j;
        u32 val = (u32)v0[j] | ((u32)v1[j] << 16);
        int sw = ((d & 7) ^ (d >> 3)) << 4;
        *(u32*)(Vb + d * 128 + ((2 * kv0) ^ sw)) = val;
      }
    }
    __syncthreads();

    // QK^T: S[16q x 64kv] per wave (B operand = K rows)
    f32x4 s_acc[4];
#pragma unroll
    for (int nb = 0; nb < 4; ++nb) {
      int kv = nb * 16 + l15;
      const char* kb = Kb + kv * 128;
      int sw = (kv & 7) << 4;
      bf16x8 kf0 = *(const bf16x8*)(kb + ((g * 16) ^ sw));
      bf16x8 kf1 = *(const bf16x8*)(kb + ((64 + g * 16) ^ sw));
      f32x4 z = {0.f, 0.f, 0.f, 0.f};
      z = __builtin_amdgcn_mfma_f32_16x16x32_bf16(qf0, kf0, z, 0, 0, 0);
      z = __builtin_amdgcn_mfma_f32_16x16x32_bf16(qf1, kf1, z, 0, 0, 0);
      s_acc[nb] = z;
    }

    bool diag = (kvt == qt);
#pragma unroll
    for (int r = 0; r < 4; ++r) {
      int qloc = w * 16 + g * 4 + r;
#pragma unroll
      for (int nb = 0; nb < 4; ++nb) {
        float s = s_acc[nb][r] * 0.125f;  // 1/sqrt(64)
        if (diag && (nb * 16 + l15) > qloc) s = -1e30f;
        s_acc[nb][r] = s;
      }
      float pm = fmaxf(fmaxf(s_acc[0][r], s_acc[1][r]), fmaxf(s_acc[2][r], s_acc[3][r]));
      pm = fmaxf(pm, __shfl_xor(pm, 1));
      pm = fmaxf(pm, __shfl_xor(pm, 2));
      pm = fmaxf(pm, __shfl_xor(pm, 4));
      pm = fmaxf(pm, __shfl_xor(pm, 8));
      float newm = fmaxf(m_r[r], pm);
      float corr = __expf(m_r[r] - newm);
      float rs = 0.f;
#pragma unroll
      for (int nb = 0; nb < 4; ++nb) {
        float p = __expf(s_acc[nb][r] - newm);
        s_acc[nb][r] = p;
        rs += p;
      }
      rs += __shfl_xor(rs, 1);
      rs += __shfl_xor(rs, 2);
      rs += __shfl_xor(rs, 4);
      rs += __shfl_xor(rs, 8);
      l_r[r] = l_r[r] * corr + rs;
      m_r[r] = newm;
#pragma unroll
      for (int nb = 0; nb < 4; ++nb) o_acc[nb][r] *= corr;
    }

    // write P (bf16) to this wave's LDS region
#pragma unroll
    for (int r = 0; r < 4; ++r) {
      int q = g * 4 + r;
      int sw = (q & 7) << 4;
#pragma unroll
      for (int nb = 0; nb < 4; ++nb) {
        int kv = nb * 16 + l15;
        *(u16*)(pw + q * 128 + ((2 * kv) ^ sw)) = f2bf(s_acc[nb][r]);
      }
    }
    __syncthreads();

    // PV: O[16q x 64d] += P[16q x 64kv] * V[64kv x 64d]
#pragma unroll
    for (int ks = 0; ks < 2; ++ks) {
      bf16x8 pf = *(const bf16x8*)(pw + l15 * 128 + ((ks * 64 + g * 16) ^ ((l15 & 7) << 4)));
#pragma unroll
      for (int nb = 0; nb < 4; ++nb) {
        int d = nb * 16 + l15;
        int sw = ((d & 7) ^ (d >> 3)) << 4;
        bf16x8 vf = *(const bf16x8*)(Vb + d * 128 + ((ks * 64 + g * 16) ^ sw));
        o_acc[nb] = __builtin_amdgcn_mfma_f32_16x16x32_bf16(pf, vf, o_acc[nb], 0, 0, 0);
      }
    }
  }

  // epilogue: normalize and store bf16 [B*S][1024] rows, col = h*64 + d
#pragma unroll
  for (int nb = 0; nb < 4; ++nb) {
    int col = h * 64 + nb * 16 + l15;
#pragma unroll
    for (int r = 0; r < 4; ++r) {
      int row = b * S + qt * 64 + w * 16 + g * 4 + r;
      aout[(size_t)row * 1024 + col] = f2bf(o_acc[nb][r] / l_r[r]);
    }
  }
}

// ---------------------------------------------------------------------------
extern "C" void kernel_launch(void* const* d_in, const int* in_sizes, int n_in,
                              void* d_out, int out_size, void* d_ws, size_t ws_size,
                              hipStream_t stream) {
  (void)in_sizes; (void)n_in; (void)out_size;
  const float* x     = (const float*)d_in[0];
  const float* w_in  = (const float*)d_in[1];
  const float* b_in  = (const float*)d_in[2];
  const float* w_out = (const float*)d_in[3];
  const float* b_out = (const float*)d_in[4];
  float* out = (float*)d_out;
  char* ws = (char*)d_ws;
  if (ws_size < 92274688u) return;  // need 88 MB

  u16* xb     = (u16*)(ws);                       // bf16 x        [8192][1024] 16 MB
  u16* w_inT  = (u16*)(ws + (16u << 20));         // bf16 w_in^T   [3072][1024]  6 MB
  u16* w_outT = (u16*)(ws + (22u << 20));         // bf16 w_out^T  [1024][1024]  2 MB
  u16* qkv    = (u16*)(ws + (24u << 20));         // bf16 qkv      [8192][3072] 48 MB
  u16* aout   = (u16*)(ws + (72u << 20));         // bf16 attn out [8192][1024] 16 MB

  conv_f32_bf16<<<4096, 256, 0, stream>>>(x, xb, 1048576);
  conv_transpose<<<768, 256, 0, stream>>>(w_in, w_inT, 1024, 3072);
  conv_transpose<<<256, 256, 0, stream>>>(w_out, w_outT, 1024, 1024);
  // qkv = x @ w_in + b_in   (M=8192, N=3072, K=1024)
  gemm_kernel<1><<<1536, 256, 0, stream>>>(xb, w_inT, b_in, qkv, 8192, 3072, 1024);
  // causal attention per (b,h), 64-row q tiles
  attn_fwd<<<2048, 256, 0, stream>>>(qkv, aout);
  // out = attn @ w_out + b_out  (M=8192, N=1024, K=1024), fp32 out
  gemm_kernel<0><<<512, 256, 0, stream>>>(aout, w_outT, b_out, out, 8192, 1024, 1024);
}

// Round 2
// 261.893 us; speedup vs baseline: 1.1382x; 1.1382x over previous
//
#include <hip/hip_runtime.h>

typedef unsigned short u16;
typedef unsigned int   u32;
typedef float  f32x4  __attribute__((ext_vector_type(4)));
typedef __bf16 bf16x8 __attribute__((ext_vector_type(8)));
typedef __bf16 bf16x4 __attribute__((ext_vector_type(4)));
typedef short  s16x4  __attribute__((ext_vector_type(4)));
typedef unsigned short u16x8 __attribute__((ext_vector_type(8)));
typedef unsigned int   u32x4 __attribute__((ext_vector_type(4)));

// fp32 -> bf16 round-to-nearest-even
__device__ __forceinline__ u16 f2bf(float f) {
  u32 u = __builtin_bit_cast(u32, f);
  u = (u + 0x7fffu + ((u >> 16) & 1u)) >> 16;
  return (u16)u;
}

// async global->LDS, 16B per lane; LDS dest is wave-uniform base (HW adds lane*16)
__device__ __forceinline__ void gload_lds16(const void* g, void* l) {
  __builtin_amdgcn_global_load_lds(
      (const __attribute__((address_space(1))) void*)g,
      (__attribute__((address_space(3))) void*)l, 16, 0, 0);
}

// ---------------------------------------------------------------------------
// fp32 -> bf16 elementwise (8 elems/thread)
__global__ __launch_bounds__(256) void conv_f32_bf16(
    const float* __restrict__ in, u16* __restrict__ out, int n8) {
  int i = blockIdx.x * 256 + threadIdx.x;
  if (i >= n8) return;
  const float4* p = (const float4*)in;
  float4 a = p[2 * i], b = p[2 * i + 1];
  u16x8 r;
  r[0] = f2bf(a.x); r[1] = f2bf(a.y); r[2] = f2bf(a.z); r[3] = f2bf(a.w);
  r[4] = f2bf(b.x); r[5] = f2bf(b.y); r[6] = f2bf(b.z); r[7] = f2bf(b.w);
  ((u16x8*)out)[i] = r;
}

// fp32 [K][N] -> bf16 [N][K] transpose (64x64 tiles via LDS)
__global__ __launch_bounds__(256) void conv_transpose(
    const float* __restrict__ in, u16* __restrict__ out, int K, int N) {
  __shared__ float tile[64][65];
  int nb = N >> 6;
  int tk = blockIdx.x / nb, tn = blockIdx.x % nb;
  int t = threadIdx.x;
  int kl = t >> 4, n4 = (t & 15) * 4;
#pragma unroll
  for (int i = 0; i < 4; ++i) {
    int k = kl + 16 * i;
    float4 v = *(const float4*)(in + (size_t)(tk * 64 + k) * N + tn * 64 + n4);
    tile[k][n4] = v.x; tile[k][n4 + 1] = v.y; tile[k][n4 + 2] = v.z; tile[k][n4 + 3] = v.w;
  }
  __syncthreads();
  int nl = t >> 4, k4 = (t & 15) * 4;
#pragma unroll
  for (int i = 0; i < 4; ++i) {
    int n = nl + 16 * i;
    ushort4 o;
    o.x = f2bf(tile[k4 + 0][n]); o.y = f2bf(tile[k4 + 1][n]);
    o.z = f2bf(tile[k4 + 2][n]); o.w = f2bf(tile[k4 + 3][n]);
    *(ushort4*)(out + (size_t)(tn * 64 + n) * K + tk * 64 + k4) = o;
  }
}

// ---------------------------------------------------------------------------
// bf16 GEMM: C[M][N] = A[M][K] * Bt[N][K]^T + bias ; 128x128 tile, BK=64,
// 4 waves (2x2), each wave 64x64 via 4x4 x mfma_f32_16x16x32_bf16.
template <int OUT_BF16>
__global__ __launch_bounds__(256, 2) void gemm_kernel(
    const u16* __restrict__ A, const u16* __restrict__ Bt,
    const float* __restrict__ bias, void* __restrict__ C,
    int M, int N, int K) {
  __shared__ __align__(16) char smem[32768];
  char* As = smem;
  char* Bs = smem + 16384;
  int tid = threadIdx.x, w = tid >> 6, lane = tid & 63;
  int g = lane >> 4, l15 = lane & 15, l7 = lane & 7;
  int nblk = N >> 7;
  int bm = blockIdx.x / nblk, bn = blockIdx.x % nblk;
  int m0 = bm << 7, n0 = bn << 7;
  int wm = w >> 1, wn = w & 1;

  f32x4 acc[4][4];
#pragma unroll
  for (int i = 0; i < 4; ++i)
#pragma unroll
    for (int j = 0; j < 4; ++j) acc[i][j] = f32x4{0.f, 0.f, 0.f, 0.f};

  int kiter = K >> 6;
  for (int kt = 0; kt < kiter; ++kt) {
    __syncthreads();
#pragma unroll
    for (int i = 0; i < 4; ++i) {
      int rbase = 32 * w + 8 * i;
      int row = rbase + (lane >> 3);
      int koff = kt * 64 + 8 * (l7 ^ (row & 7));
      gload_lds16(A + (size_t)(m0 + row) * K + koff, As + rbase * 128);
      gload_lds16(Bt + (size_t)(n0 + row) * K + koff, Bs + rbase * 128);
    }
    __syncthreads();
#pragma unroll
    for (int ks = 0; ks < 2; ++ks) {
      bf16x8 af[4], bf[4];
#pragma unroll
      for (int mi = 0; mi < 4; ++mi) {
        int ml = wm * 64 + mi * 16 + l15;
        af[mi] = *(const bf16x8*)(As + ml * 128 + ((ks * 64 + g * 16) ^ ((ml & 7) << 4)));
      }
#pragma unroll
      for (int ni = 0; ni < 4; ++ni) {
        int nl = wn * 64 + ni * 16 + l15;
        bf[ni] = *(const bf16x8*)(Bs + nl * 128 + ((ks * 64 + g * 16) ^ ((nl & 7) << 4)));
      }
#pragma unroll
      for (int mi = 0; mi < 4; ++mi)
#pragma unroll
        for (int ni = 0; ni < 4; ++ni)
          acc[mi][ni] = __builtin_amdgcn_mfma_f32_16x16x32_bf16(af[mi], bf[ni], acc[mi][ni], 0, 0, 0);
    }
  }

#pragma unroll
  for (int ni = 0; ni < 4; ++ni) {
    int col = n0 + wn * 64 + ni * 16 + l15;
    float bv = bias[col];
#pragma unroll
    for (int mi = 0; mi < 4; ++mi) {
      int rowb = m0 + wm * 64 + mi * 16 + g * 4;
#pragma unroll
      for (int r = 0; r < 4; ++r) {
        float v = acc[mi][ni][r] + bv;
        if (OUT_BF16)
          ((u16*)C)[(size_t)(rowb + r) * N + col] = f2bf(v);
        else
          ((float*)C)[(size_t)(rowb + r) * N + col] = v;
      }
    }
  }
}

// ---------------------------------------------------------------------------
// Causal flash attention, swapped-QK^T (S^T in registers) + in-register softmax.
// qkv bf16 [B*S][3072]; q cols [0,1024), k [1024,2048), v [2048,3072); head h
// owns 64 cols. Block = one (b,h) x 64 q-rows; 4 waves x 16 q-rows. KVBLK=64.
// Double-buffered K (gload_lds, swizzled src) and V^T (reg-staged transpose).

#if __has_builtin(__builtin_amdgcn_mfma_f32_16x16x16bf16_1k)
#define HAVE_MFMA16 1
__device__ __forceinline__ f32x4 mfma16(s16x4 a, s16x4 b, f32x4 c) {
  return __builtin_amdgcn_mfma_f32_16x16x16bf16_1k(a, b, c, 0, 0, 0);
}
#endif

struct V2reg { u16x8 a, b; };

__device__ __forceinline__ void stage_k(const u16* qb, char* kbuf, int kvt,
                                        int h, int w, int lane) {
  int l7 = lane & 7;
#pragma unroll
  for (int i = 0; i < 2; ++i) {
    int rbase = w * 16 + i * 8;
    int row = rbase + (lane >> 3);
    const u16* src = qb + (size_t)(kvt * 64 + row) * 3072 + 1024 + h * 64 + 8 * (l7 ^ (row & 7));
    gload_lds16(src, kbuf + rbase * 128);
  }
}

__device__ __forceinline__ V2reg load_v(const u16* qb, int kvt, int h, int kv0, int d0) {
  const u16* vs = qb + (size_t)(kvt * 64 + kv0) * 3072 + 2048 + h * 64 + d0;
  V2reg r;
  r.a = *(const u16x8*)vs;
  r.b = *(const u16x8*)(vs + 3072);
  return r;
}

__device__ __forceinline__ void write_v(char* vbuf, V2reg v, int kv0, int d0) {
#pragma unroll
  for (int j = 0; j < 8; ++j) {
    int d = d0 + j;
    u32 val = (u32)v.a[j] | ((u32)v.b[j] << 16);
    int sw = ((d & 7) ^ (d >> 3)) << 4;
    *(u32*)(vbuf + d * 128 + ((2 * kv0) ^ sw)) = val;
  }
}

__global__ __launch_bounds__(256, 2) void attn_fwd(
    const u16* __restrict__ qkv, u16* __restrict__ aout) {
  const int S = 2048, D3 = 3072;
  int bh = blockIdx.x & 63;
  int qt = 31 - (blockIdx.x >> 6);  // heavy tiles first
  int b = bh >> 4, h = bh & 15;
  const u16* qb = qkv + (size_t)b * S * D3;

  int tid = threadIdx.x;
  int w = tid >> 6, lane = tid & 63;
  int g = lane >> 4, l15 = lane & 15, l7 = lane & 7;

  __shared__ __align__(16) char Kb[2][8192];  // K [64 kv][64 d], (kv&7) swizzle
  __shared__ __align__(16) char Vb[2][8192];  // V^T [64 d][64 kv], ((d&7)^(d>>3)) swizzle

  // Q fragments: rows qt*64 + w*16 + l15, k = ks*32 + g*8 + j
  int qrow = qt * 64 + w * 16 + l15;
  const u16* qp = qb + (size_t)qrow * D3 + h * 64 + g * 8;
  bf16x8 qf0 = *(const bf16x8*)qp;
  bf16x8 qf1 = *(const bf16x8*)(qp + 32);

  f32x4 oaT[4];  // O^T: col=q=l15, row: d = db*16 + g*4 + r
#pragma unroll
  for (int i = 0; i < 4; ++i) oaT[i] = f32x4{0.f, 0.f, 0.f, 0.f};
  float m_s = -3e38f, l_s = 0.f;  // per-lane (one q per lane)

  int vkv0 = w * 16 + ((lane >> 3) << 1);
  int vd0 = l7 * 8;

  // prologue: stage tile 0
  stage_k(qb, Kb[0], 0, h, w, lane);
  {
    V2reg v = load_v(qb, 0, h, vkv0, vd0);
    write_v(Vb[0], v, vkv0, vd0);
  }
  __syncthreads();

  V2reg vreg;
  for (int kvt = 0; kvt <= qt; ++kvt) {
    int cur = kvt & 1;
    if (kvt < qt) {  // prefetch next tile while computing this one
      stage_k(qb, Kb[cur ^ 1], kvt + 1, h, w, lane);
      vreg = load_v(qb, kvt + 1, h, vkv0, vd0);
    }

    // QK^T swapped: sT[nb] = S^T tile, col=q=l15, row=kv= nb*16 + g*4 + r
    f32x4 sT[4];
    __builtin_amdgcn_s_setprio(1);
#pragma unroll
    for (int nb = 0; nb < 4; ++nb) {
      int kv = nb * 16 + l15;
      const char* kb = Kb[cur] + kv * 128;
      int sw = (kv & 7) << 4;
      bf16x8 kf0 = *(const bf16x8*)(kb + ((g * 16) ^ sw));
      bf16x8 kf1 = *(const bf16x8*)(kb + ((64 + g * 16) ^ sw));
      f32x4 z = {0.f, 0.f, 0.f, 0.f};
      z = __builtin_amdgcn_mfma_f32_16x16x32_bf16(kf0, qf0, z, 0, 0, 0);
      z = __builtin_amdgcn_mfma_f32_16x16x32_bf16(kf1, qf1, z, 0, 0, 0);
      sT[nb] = z;
    }
    __builtin_amdgcn_s_setprio(0);

    // scale + causal mask (mask only on diagonal tile; wave-uniform branch)
#pragma unroll
    for (int nb = 0; nb < 4; ++nb)
#pragma unroll
      for (int r = 0; r < 4; ++r) sT[nb][r] *= 0.125f;  // 1/sqrt(64)
    if (kvt == qt) {
      int qloc = w * 16 + l15;
#pragma unroll
      for (int nb = 0; nb < 4; ++nb)
#pragma unroll
        for (int r = 0; r < 4; ++r)
          if (nb * 16 + g * 4 + r > qloc) sT[nb][r] = -1e30f;
    }

    // online softmax: in-lane over 16 kv, then cross-g (2 shfls)
    float pm = -3e38f;
#pragma unroll
    for (int nb = 0; nb < 4; ++nb)
#pragma unroll
      for (int r = 0; r < 4; ++r) pm = fmaxf(pm, sT[nb][r]);
    pm = fmaxf(pm, __shfl_xor(pm, 16));
    pm = fmaxf(pm, __shfl_xor(pm, 32));
    float newm = fmaxf(m_s, pm);
    float corr = __expf(m_s - newm);
    float rs = 0.f;
#pragma unroll
    for (int nb = 0; nb < 4; ++nb)
#pragma unroll
      for (int r = 0; r < 4; ++r) {
        float e = __expf(sT[nb][r] - newm);
        sT[nb][r] = e;
        rs += e;
      }
    rs += __shfl_xor(rs, 16);
    rs += __shfl_xor(rs, 32);
    l_s = l_s * corr + rs;
    m_s = newm;
#pragma unroll
    for (int db = 0; db < 4; ++db)
#pragma unroll
      for (int r = 0; r < 4; ++r) oaT[db][r] *= corr;

#ifdef HAVE_MFMA16
    // P^T fragments: lane holds P^T[kv=nb*16+g*4+j][q=l15] == B-operand of 16x16x16
    s16x4 pf[4];
#pragma unroll
    for (int nb = 0; nb < 4; ++nb) {
      bf16x4 t;
#pragma unroll
      for (int r = 0; r < 4; ++r) t[r] = (__bf16)sT[nb][r];
      pf[nb] = __builtin_bit_cast(s16x4, t);
    }
    // PV: O^T[d][q] += V^T[d][kv] * P^T[kv][q]
    __builtin_amdgcn_s_setprio(1);
#pragma unroll
    for (int db = 0; db < 4; ++db) {
      int d = db * 16 + l15;
      const char* vb = Vb[cur] + d * 128;
      int swd = ((d & 7) ^ (d >> 3)) << 4;
#pragma unroll
      for (int nb = 0; nb < 4; ++nb) {
        bf16x4 vf = *(const bf16x4*)(vb + ((nb * 32 + g * 8) ^ swd));
        oaT[db] = mfma16(__builtin_bit_cast(s16x4, vf), pf[nb], oaT[db]);
      }
    }
    __builtin_amdgcn_s_setprio(0);
#else
    // fallback: build x32 B-fragments via bpermute exchange
    u32 wlo[4], whi[4];
#pragma unroll
    for (int nb = 0; nb < 4; ++nb) {
      wlo[nb] = (u32)f2bf(sT[nb][0]) | ((u32)f2bf(sT[nb][1]) << 16);
      whi[nb] = (u32)f2bf(sT[nb][2]) | ((u32)f2bf(sT[nb][3]) << 16);
    }
    int srcA = (2 * (g & 1)) * 16 + l15;
    int srcB = srcA + 16;
    bool hi = (g >> 1) != 0;
    __builtin_amdgcn_s_setprio(1);
#pragma unroll
    for (int kb2 = 0; kb2 < 2; ++kb2) {
      int nbE = kb2 * 2, nbO = kb2 * 2 + 1;
      u32 a0 = __shfl(wlo[nbE], srcA), a1 = __shfl(whi[nbE], srcA);
      u32 a2 = __shfl(wlo[nbE], srcB), a3 = __shfl(whi[nbE], srcB);
      u32 b0 = __shfl(wlo[nbO], srcA), b1 = __shfl(whi[nbO], srcA);
      u32 b2 = __shfl(wlo[nbO], srcB), b3 = __shfl(whi[nbO], srcB);
      u32x4 ow = {hi ? b0 : a0, hi ? b1 : a1, hi ? b2 : a2, hi ? b3 : a3};
      bf16x8 pfrag = __builtin_bit_cast(bf16x8, ow);
#pragma unroll
      for (int db = 0; db < 4; ++db) {
        int d = db * 16 + l15;
        int swd = ((d & 7) ^ (d >> 3)) << 4;
        bf16x8 vf = *(const bf16x8*)(Vb[cur] + d * 128 + ((kb2 * 64 + g * 16) ^ swd));
        oaT[db] = __builtin_amdgcn_mfma_f32_16x16x32_bf16(vf, pfrag, oaT[db], 0, 0, 0);
      }
    }
    __builtin_amdgcn_s_setprio(0);
#endif

    if (kvt < qt) {
      write_v(Vb[cur ^ 1], vreg, vkv0, vd0);
      __syncthreads();
    }
  }

  // epilogue: lane owns q=l15; d = db*16 + g*4 + r
  float inv = 1.0f / l_s;
  size_t obase = (size_t)(b * S + qt * 64 + w * 16 + l15) * 1024 + h * 64;
#pragma unroll
  for (int db = 0; db < 4; ++db) {
    ushort4 st;
    st.x = f2bf(oaT[db][0] * inv);
    st.y = f2bf(oaT[db][1] * inv);
    st.z = f2bf(oaT[db][2] * inv);
    st.w = f2bf(oaT[db][3] * inv);
    *(ushort4*)(aout + obase + db * 16 + g * 4) = st;
  }
}

// ---------------------------------------------------------------------------
extern "C" void kernel_launch(void* const* d_in, const int* in_sizes, int n_in,
                              void* d_out, int out_size, void* d_ws, size_t ws_size,
                              hipStream_t stream) {
  (void)in_sizes; (void)n_in; (void)out_size;
  const float* x     = (const float*)d_in[0];
  const float* w_in  = (const float*)d_in[1];
  const float* b_in  = (const float*)d_in[2];
  const float* w_out = (const float*)d_in[3];
  const float* b_out = (const float*)d_in[4];
  float* out = (float*)d_out;
  char* ws = (char*)d_ws;
  if (ws_size < 92274688u) return;  // need 88 MB

  u16* xb     = (u16*)(ws);                // bf16 x        [8192][1024] 16 MB
  u16* w_inT  = (u16*)(ws + (16u << 20));  // bf16 w_in^T   [3072][1024]  6 MB
  u16* w_outT = (u16*)(ws + (22u << 20));  // bf16 w_out^T  [1024][1024]  2 MB
  u16* qkv    = (u16*)(ws + (24u << 20));  // bf16 qkv      [8192][3072] 48 MB
  u16* aout   = (u16*)(ws + (72u << 20));  // bf16 attn out [8192][1024] 16 MB

  conv_f32_bf16<<<4096, 256, 0, stream>>>(x, xb, 1048576);
  conv_transpose<<<768, 256, 0, stream>>>(w_in, w_inT, 1024, 3072);
  conv_transpose<<<256, 256, 0, stream>>>(w_out, w_outT, 1024, 1024);
  gemm_kernel<1><<<1536, 256, 0, stream>>>(xb, w_inT, b_in, qkv, 8192, 3072, 1024);
  attn_fwd<<<2048, 256, 0, stream>>>(qkv, aout);
  gemm_kernel<0><<<512, 256, 0, stream>>>(aout, w_outT, b_out, out, 8192, 1024, 1024);
}

// Round 4
// 259.176 us; speedup vs baseline: 1.1501x; 1.0105x over previous
//
#include <hip/hip_runtime.h>

typedef unsigned short u16;
typedef unsigned int   u32;
typedef float  f32x4  __attribute__((ext_vector_type(4)));
typedef __bf16 bf16x8 __attribute__((ext_vector_type(8)));
typedef __bf16 bf16x4 __attribute__((ext_vector_type(4)));
typedef short  s16x4  __attribute__((ext_vector_type(4)));
typedef unsigned short u16x8 __attribute__((ext_vector_type(8)));
typedef unsigned int   u32x4 __attribute__((ext_vector_type(4)));

// fp32 -> bf16 round-to-nearest-even
__device__ __forceinline__ u16 f2bf(float f) {
  u32 u = __builtin_bit_cast(u32, f);
  u = (u + 0x7fffu + ((u >> 16) & 1u)) >> 16;
  return (u16)u;
}

// async global->LDS, 16B per lane; LDS dest is wave-uniform base (HW adds lane*16)
__device__ __forceinline__ void gload_lds16(const void* g, void* l) {
  __builtin_amdgcn_global_load_lds(
      (const __attribute__((address_space(1))) void*)g,
      (__attribute__((address_space(3))) void*)l, 16, 0, 0);
}

// ---------------------------------------------------------------------------
// fp32 -> bf16 elementwise (8 elems/thread)
__global__ __launch_bounds__(256) void conv_f32_bf16(
    const float* __restrict__ in, u16* __restrict__ out, int n8) {
  int i = blockIdx.x * 256 + threadIdx.x;
  if (i >= n8) return;
  const float4* p = (const float4*)in;
  float4 a = p[2 * i], b = p[2 * i + 1];
  u16x8 r;
  r[0] = f2bf(a.x); r[1] = f2bf(a.y); r[2] = f2bf(a.z); r[3] = f2bf(a.w);
  r[4] = f2bf(b.x); r[5] = f2bf(b.y); r[6] = f2bf(b.z); r[7] = f2bf(b.w);
  ((u16x8*)out)[i] = r;
}

// fp32 [K][N] -> bf16 [N][K] transpose (64x64 tiles via LDS)
__global__ __launch_bounds__(256) void conv_transpose(
    const float* __restrict__ in, u16* __restrict__ out, int K, int N) {
  __shared__ float tile[64][65];
  int nb = N >> 6;
  int tk = blockIdx.x / nb, tn = blockIdx.x % nb;
  int t = threadIdx.x;
  int kl = t >> 4, n4 = (t & 15) * 4;
#pragma unroll
  for (int i = 0; i < 4; ++i) {
    int k = kl + 16 * i;
    float4 v = *(const float4*)(in + (size_t)(tk * 64 + k) * N + tn * 64 + n4);
    tile[k][n4] = v.x; tile[k][n4 + 1] = v.y; tile[k][n4 + 2] = v.z; tile[k][n4 + 3] = v.w;
  }
  __syncthreads();
  int nl = t >> 4, k4 = (t & 15) * 4;
#pragma unroll
  for (int i = 0; i < 4; ++i) {
    int n = nl + 16 * i;
    ushort4 o;
    o.x = f2bf(tile[k4 + 0][n]); o.y = f2bf(tile[k4 + 1][n]);
    o.z = f2bf(tile[k4 + 2][n]); o.w = f2bf(tile[k4 + 3][n]);
    *(ushort4*)(out + (size_t)(tn * 64 + n) * K + tk * 64 + k4) = o;
  }
}

// ---------------------------------------------------------------------------
// bf16 GEMM: C[M][N] = A[M][K] * Bt[N][K]^T + bias ; 128x128 tile, BK=64,
// 4 waves (2x2), each wave 64x64 via 4x4 x mfma_f32_16x16x32_bf16.
// SCALE_Q: multiply cols [0,1024) by 0.125*log2e (pre-scales attention Q).
template <int OUT_BF16, int SCALE_Q>
__global__ __launch_bounds__(256, 2) void gemm_kernel(
    const u16* __restrict__ A, const u16* __restrict__ Bt,
    const float* __restrict__ bias, void* __restrict__ C,
    int M, int N, int K) {
  __shared__ __align__(16) char smem[32768];
  char* As = smem;
  char* Bs = smem + 16384;
  int tid = threadIdx.x, w = tid >> 6, lane = tid & 63;
  int g = lane >> 4, l15 = lane & 15, l7 = lane & 7;
  // T1: XCD-bijective block swizzle (grid % 8 == 0 in all our launches)
  int cpx = (int)gridDim.x >> 3;
  int bid = (blockIdx.x & 7) * cpx + (blockIdx.x >> 3);
  int nblk = N >> 7;
  int bm = bid / nblk, bn = bid % nblk;
  int m0 = bm << 7, n0 = bn << 7;
  int wm = w >> 1, wn = w & 1;

  f32x4 acc[4][4];
#pragma unroll
  for (int i = 0; i < 4; ++i)
#pragma unroll
    for (int j = 0; j < 4; ++j) acc[i][j] = f32x4{0.f, 0.f, 0.f, 0.f};

  int kiter = K >> 6;
  for (int kt = 0; kt < kiter; ++kt) {
    __syncthreads();
#pragma unroll
    for (int i = 0; i < 4; ++i) {
      int rbase = 32 * w + 8 * i;
      int row = rbase + (lane >> 3);
      int koff = kt * 64 + 8 * (l7 ^ (row & 7));
      gload_lds16(A + (size_t)(m0 + row) * K + koff, As + rbase * 128);
      gload_lds16(Bt + (size_t)(n0 + row) * K + koff, Bs + rbase * 128);
    }
    __syncthreads();
#pragma unroll
    for (int ks = 0; ks < 2; ++ks) {
      bf16x8 af[4], bf[4];
#pragma unroll
      for (int mi = 0; mi < 4; ++mi) {
        int ml = wm * 64 + mi * 16 + l15;
        af[mi] = *(const bf16x8*)(As + ml * 128 + ((ks * 64 + g * 16) ^ ((ml & 7) << 4)));
      }
#pragma unroll
      for (int ni = 0; ni < 4; ++ni) {
        int nl = wn * 64 + ni * 16 + l15;
        bf[ni] = *(const bf16x8*)(Bs + nl * 128 + ((ks * 64 + g * 16) ^ ((nl & 7) << 4)));
      }
#pragma unroll
      for (int mi = 0; mi < 4; ++mi)
#pragma unroll
        for (int ni = 0; ni < 4; ++ni)
          acc[mi][ni] = __builtin_amdgcn_mfma_f32_16x16x32_bf16(af[mi], bf[ni], acc[mi][ni], 0, 0, 0);
    }
  }

#pragma unroll
  for (int ni = 0; ni < 4; ++ni) {
    int col = n0 + wn * 64 + ni * 16 + l15;
    float bv = bias[col];
    float sc = (SCALE_Q && col < 1024) ? 0.18033688011112042f : 1.0f;  // log2e/8
#pragma unroll
    for (int mi = 0; mi < 4; ++mi) {
      int rowb = m0 + wm * 64 + mi * 16 + g * 4;
#pragma unroll
      for (int r = 0; r < 4; ++r) {
        float v = (acc[mi][ni][r] + bv) * sc;
        if (OUT_BF16)
          ((u16*)C)[(size_t)(rowb + r) * N + col] = f2bf(v);
        else
          ((float*)C)[(size_t)(rowb + r) * N + col] = v;
      }
    }
  }
}

// ---------------------------------------------------------------------------
// Causal flash attention, swapped-QK^T (S^T in registers), in-register softmax
// in log2 domain (Q pre-scaled by 0.125*log2e in GEMM1), denominator via
// ones-MFMA, defer-max rescale (THR=8 log2 units -> P <= 256).
// qkv bf16 [B*S][3072]; head h owns 64 cols of each of q/k/v sections.
// Block = one (b,h) x 64 q-rows; 4 waves x 16 q-rows. KVBLK=64, double-buffered.

#if __has_builtin(__builtin_amdgcn_mfma_f32_16x16x16bf16_1k)
#define HAVE_MFMA16 1
__device__ __forceinline__ f32x4 mfma16(s16x4 a, s16x4 b, f32x4 c) {
  return __builtin_amdgcn_mfma_f32_16x16x16bf16_1k(a, b, c, 0, 0, 0);
}
#endif

struct V2reg { u16x8 a, b; };

__device__ __forceinline__ void stage_k(const u16* qb, char* kbuf, int kvt,
                                        int h, int w, int lane) {
  int l7 = lane & 7;
#pragma unroll
  for (int i = 0; i < 2; ++i) {
    int rbase = w * 16 + i * 8;
    int row = rbase + (lane >> 3);
    const u16* src = qb + (size_t)(kvt * 64 + row) * 3072 + 1024 + h * 64 + 8 * (l7 ^ (row & 7));
    gload_lds16(src, kbuf + rbase * 128);
  }
}

__device__ __forceinline__ V2reg load_v(const u16* qb, int kvt, int h, int kv0, int d0) {
  const u16* vs = qb + (size_t)(kvt * 64 + kv0) * 3072 + 2048 + h * 64 + d0;
  V2reg r;
  r.a = *(const u16x8*)vs;
  r.b = *(const u16x8*)(vs + 3072);
  return r;
}

__device__ __forceinline__ void write_v(char* vbuf, V2reg v, int kv0, int d0) {
#pragma unroll
  for (int j = 0; j < 8; ++j) {
    int d = d0 + j;
    u32 val = (u32)v.a[j] | ((u32)v.b[j] << 16);
    int sw = ((d & 7) ^ (d >> 3)) << 4;
    *(u32*)(vbuf + d * 128 + ((2 * kv0) ^ sw)) = val;
  }
}

__global__ __launch_bounds__(256, 4) void attn_fwd(
    const u16* __restrict__ qkv, u16* __restrict__ aout) {
  const int S = 2048, D3 = 3072;
  int bh = blockIdx.x & 63;
  int qt = 31 - (blockIdx.x >> 6);  // heavy tiles first
  int b = bh >> 4, h = bh & 15;
  const u16* qb = qkv + (size_t)b * S * D3;

  int tid = threadIdx.x;
  int w = tid >> 6, lane = tid & 63;
  int g = lane >> 4, l15 = lane & 15, l7 = lane & 7;

  __shared__ __align__(16) char Kb[2][8192];  // K [64 kv][64 d], (kv&7) swizzle
  __shared__ __align__(16) char Vb[2][8192];  // V^T [64 d][64 kv], ((d&7)^(d>>3)) swizzle

  // Q fragments (already scaled by log2e/8): rows qt*64+w*16+l15, k=ks*32+g*8+j
  int qrow = qt * 64 + w * 16 + l15;
  const u16* qp = qb + (size_t)qrow * D3 + h * 64 + g * 8;
  bf16x8 qf0 = *(const bf16x8*)qp;
  bf16x8 qf1 = *(const bf16x8*)(qp + 32);

  f32x4 oaT[4];  // O^T: col=q=l15, row d = db*16 + g*4 + r
#pragma unroll
  for (int i = 0; i < 4; ++i) oaT[i] = f32x4{0.f, 0.f, 0.f, 0.f};
  f32x4 l_acc = {0.f, 0.f, 0.f, 0.f};  // denominator (ones-MFMA); use [0]
  float m_s = -3e38f;

  int vkv0 = w * 16 + ((lane >> 3) << 1);
  int vd0 = l7 * 8;

  // prologue: stage tile 0
  stage_k(qb, Kb[0], 0, h, w, lane);
  {
    V2reg v = load_v(qb, 0, h, vkv0, vd0);
    write_v(Vb[0], v, vkv0, vd0);
  }
  __syncthreads();

  V2reg vreg;
  for (int kvt = 0; kvt <= qt; ++kvt) {
    int cur = kvt & 1;
    if (kvt < qt) {  // prefetch next tile while computing this one
      stage_k(qb, Kb[cur ^ 1], kvt + 1, h, w, lane);
      vreg = load_v(qb, kvt + 1, h, vkv0, vd0);
    }

    // QK^T swapped: sT[nb] = S^T tile (log2-scaled), col=q=l15, row=kv=nb*16+g*4+r
    f32x4 sT[4];
    __builtin_amdgcn_s_setprio(1);
#pragma unroll
    for (int nb = 0; nb < 4; ++nb) {
      int kv = nb * 16 + l15;
      const char* kb = Kb[cur] + kv * 128;
      int sw = (kv & 7) << 4;
      bf16x8 kf0 = *(const bf16x8*)(kb + ((g * 16) ^ sw));
      bf16x8 kf1 = *(const bf16x8*)(kb + ((64 + g * 16) ^ sw));
      f32x4 z = {0.f, 0.f, 0.f, 0.f};
      z = __builtin_amdgcn_mfma_f32_16x16x32_bf16(kf0, qf0, z, 0, 0, 0);
      z = __builtin_amdgcn_mfma_f32_16x16x32_bf16(kf1, qf1, z, 0, 0, 0);
      sT[nb] = z;
    }
    __builtin_amdgcn_s_setprio(0);

    // causal mask on diagonal tile (wave-uniform branch)
    if (kvt == qt) {
      int qloc = w * 16 + l15;
#pragma unroll
      for (int nb = 0; nb < 4; ++nb)
#pragma unroll
        for (int r = 0; r < 4; ++r)
          if (nb * 16 + g * 4 + r > qloc) sT[nb][r] = -1e30f;
    }

    // online softmax (log2 domain), defer-max
    float pm = -3e38f;
#pragma unroll
    for (int nb = 0; nb < 4; ++nb)
#pragma unroll
      for (int r = 0; r < 4; ++r) pm = fmaxf(pm, sT[nb][r]);
    pm = fmaxf(pm, __shfl_xor(pm, 16));
    pm = fmaxf(pm, __shfl_xor(pm, 32));
    if (!__all(pm - m_s <= 8.0f)) {
      float newm = fmaxf(m_s, pm);
      float corr = __builtin_amdgcn_exp2f(m_s - newm);
      m_s = newm;
      l_acc[0] *= corr;
#pragma unroll
      for (int db = 0; db < 4; ++db)
#pragma unroll
        for (int r = 0; r < 4; ++r) oaT[db][r] *= corr;
    }
#pragma unroll
    for (int nb = 0; nb < 4; ++nb)
#pragma unroll
      for (int r = 0; r < 4; ++r)
        sT[nb][r] = __builtin_amdgcn_exp2f(sT[nb][r] - m_s);

#ifdef HAVE_MFMA16
    // P^T fragments: lane holds P^T[kv=nb*16+g*4+j][q=l15] == B-operand of 16x16x16
    s16x4 pf[4];
#pragma unroll
    for (int nb = 0; nb < 4; ++nb) {
      bf16x4 t;
#pragma unroll
      for (int r = 0; r < 4; ++r) t[r] = (__bf16)sT[nb][r];
      pf[nb] = __builtin_bit_cast(s16x4, t);
    }
    s16x4 ones;
#pragma unroll
    for (int r = 0; r < 4; ++r) ones[r] = (short)0x3F80;  // bf16 1.0
    // PV: O^T[d][q] += V^T[d][kv] * P^T[kv][q]; denominator via ones-A MFMA
    __builtin_amdgcn_s_setprio(1);
#pragma unroll
    for (int nb = 0; nb < 4; ++nb) l_acc = mfma16(ones, pf[nb], l_acc);
#pragma unroll
    for (int db = 0; db < 4; ++db) {
      int d = db * 16 + l15;
      const char* vb = Vb[cur] + d * 128;
      int swd = ((d & 7) ^ (d >> 3)) << 4;
#pragma unroll
      for (int nb = 0; nb < 4; ++nb) {
        bf16x4 vf = *(const bf16x4*)(vb + ((nb * 32 + g * 8) ^ swd));
        oaT[db] = mfma16(__builtin_bit_cast(s16x4, vf), pf[nb], oaT[db]);
      }
    }
    __builtin_amdgcn_s_setprio(0);
#else
    // fallback: build x32 B-fragments via shfl exchange; denominator via ones-A
    u32 wlo[4], whi[4];
#pragma unroll
    for (int nb = 0; nb < 4; ++nb) {
      wlo[nb] = (u32)f2bf(sT[nb][0]) | ((u32)f2bf(sT[nb][1]) << 16);
      whi[nb] = (u32)f2bf(sT[nb][2]) | ((u32)f2bf(sT[nb][3]) << 16);
    }
    int srcA = (2 * (g & 1)) * 16 + l15;
    int srcB = srcA + 16;
    bool hi = (g >> 1) != 0;
    bf16x8 ones8;
#pragma unroll
    for (int j = 0; j < 8; ++j) ones8[j] = __builtin_bit_cast(__bf16, (u16)0x3F80);
    __builtin_amdgcn_s_setprio(1);
#pragma unroll
    for (int kb2 = 0; kb2 < 2; ++kb2) {
      int nbE = kb2 * 2, nbO = kb2 * 2 + 1;
      u32 a0 = __shfl(wlo[nbE], srcA), a1 = __shfl(whi[nbE], srcA);
      u32 a2 = __shfl(wlo[nbE], srcB), a3 = __shfl(whi[nbE], srcB);
      u32 b0 = __shfl(wlo[nbO], srcA), b1 = __shfl(whi[nbO], srcA);
      u32 b2 = __shfl(wlo[nbO], srcB), b3 = __shfl(whi[nbO], srcB);
      u32x4 ow = {hi ? b0 : a0, hi ? b1 : a1, hi ? b2 : a2, hi ? b3 : a3};
      bf16x8 pfrag = __builtin_bit_cast(bf16x8, ow);
      l_acc = __builtin_amdgcn_mfma_f32_16x16x32_bf16(ones8, pfrag, l_acc, 0, 0, 0);
#pragma unroll
      for (int db = 0; db < 4; ++db) {
        int d = db * 16 + l15;
        int swd = ((d & 7) ^ (d >> 3)) << 4;
        bf16x8 vf = *(const bf16x8*)(Vb[cur] + d * 128 + ((kb2 * 64 + g * 16) ^ swd));
        oaT[db] = __builtin_amdgcn_mfma_f32_16x16x32_bf16(vf, pfrag, oaT[db], 0, 0, 0);
      }
    }
    __builtin_amdgcn_s_setprio(0);
#endif

    if (kvt < qt) {
      write_v(Vb[cur ^ 1], vreg, vkv0, vd0);
      __syncthreads();
    }
  }

  // epilogue: lane owns q=l15; d = db*16 + g*4 + r
  float inv = 1.0f / l_acc[0];
  size_t obase = (size_t)(b * S + qt * 64 + w * 16 + l15) * 1024 + h * 64;
#pragma unroll
  for (int db = 0; db < 4; ++db) {
    ushort4 st;
    st.x = f2bf(oaT[db][0] * inv);
    st.y = f2bf(oaT[db][1] * inv);
    st.z = f2bf(oaT[db][2] * inv);
    st.w = f2bf(oaT[db][3] * inv);
    *(ushort4*)(aout + obase + db * 16 + g * 4) = st;
  }
}

// ---------------------------------------------------------------------------
extern "C" void kernel_launch(void* const* d_in, const int* in_sizes, int n_in,
                              void* d_out, int out_size, void* d_ws, size_t ws_size,
                              hipStream_t stream) {
  (void)in_sizes; (void)n_in; (void)out_size;
  const float* x     = (const float*)d_in[0];
  const float* w_in  = (const float*)d_in[1];
  const float* b_in  = (const float*)d_in[2];
  const float* w_out = (const float*)d_in[3];
  const float* b_out = (const float*)d_in[4];
  float* out = (float*)d_out;
  char* ws = (char*)d_ws;
  if (ws_size < 92274688u) return;  // need 88 MB

  u16* xb     = (u16*)(ws);                // bf16 x        [8192][1024] 16 MB
  u16* w_inT  = (u16*)(ws + (16u << 20));  // bf16 w_in^T   [3072][1024]  6 MB
  u16* w_outT = (u16*)(ws + (22u << 20));  // bf16 w_out^T  [1024][1024]  2 MB
  u16* qkv    = (u16*)(ws + (24u << 20));  // bf16 qkv      [8192][3072] 48 MB
  u16* aout   = (u16*)(ws + (72u << 20));  // bf16 attn out [8192][1024] 16 MB

  conv_f32_bf16<<<4096, 256, 0, stream>>>(x, xb, 1048576);
  conv_transpose<<<768, 256, 0, stream>>>(w_in, w_inT, 1024, 3072);
  conv_transpose<<<256, 256, 0, stream>>>(w_out, w_outT, 1024, 1024);
  gemm_kernel<1, 1><<<1536, 256, 0, stream>>>(xb, w_inT, b_in, qkv, 8192, 3072, 1024);
  attn_fwd<<<2048, 256, 0, stream>>>(qkv, aout);
  gemm_kernel<0, 0><<<512, 256, 0, stream>>>(aout, w_outT, b_out, out, 8192, 1024, 1024);
}